// Round 11
// baseline (451.371 us; speedup 1.0000x reference)
//
#include <hip/hip_runtime.h>
#include <math.h>

#define NBINS 256
#define HIST_COPIES 32
#define HIST_BLOCKS 2048
#define GATH_BLOCKS 2048

typedef float vfloat4 __attribute__((ext_vector_type(4)));
typedef unsigned int vuint4 __attribute__((ext_vector_type(4)));

__device__ __forceinline__ int quant_idx(float s) {
    // reference: clip(floor((s+1)/2*255), 0, 255)
    float t = floorf((s + 1.0f) * 0.5f * 255.0f);
    t = fminf(fmaxf(t, 0.0f), 255.0f);
    return (int)t;
}

__device__ __forceinline__ unsigned int quant_pack4(vfloat4 v,
                                                    unsigned int* lh_wave) {
    int i0 = quant_idx(v.x);
    int i1 = quant_idx(v.y);
    int i2 = quant_idx(v.z);
    int i3 = quant_idx(v.w);
    atomicAdd(&lh_wave[i0], 1u);
    atomicAdd(&lh_wave[i1], 1u);
    atomicAdd(&lh_wave[i2], 1u);
    atomicAdd(&lh_wave[i3], 1u);
    return (unsigned int)i0 | ((unsigned int)i1 << 8) |
           ((unsigned int)i2 << 16) | ((unsigned int)i3 << 24);
}

// ---- Pass 1: each thread owns a 64B chunk/iter: 4 nt float4 loads (same
//      cache line), 16 LDS-atomic increments, one uint4 idx store (cached:
//      want idx L3-resident for pass 2).
template <bool STORE_IDX>
__global__ __launch_bounds__(256) void hist_kernel(
    const float* __restrict__ src, unsigned int* __restrict__ copies,
    vuint4* __restrict__ idx16_out, int n16, int n) {
    __shared__ unsigned int lh[4][NBINS];
    const int tid = threadIdx.x;
    const int wave = tid >> 6;
    for (int i = tid; i < 4 * NBINS; i += 256) ((unsigned int*)lh)[i] = 0u;
    __syncthreads();

    const int stride = gridDim.x * 256;
    const vfloat4* src4 = (const vfloat4*)src;
    for (int c = blockIdx.x * 256 + tid; c < n16; c += stride) {
        vfloat4 v0 = __builtin_nontemporal_load(&src4[4 * c + 0]);
        vfloat4 v1 = __builtin_nontemporal_load(&src4[4 * c + 1]);
        vfloat4 v2 = __builtin_nontemporal_load(&src4[4 * c + 2]);
        vfloat4 v3 = __builtin_nontemporal_load(&src4[4 * c + 3]);
        vuint4 w;
        w.x = quant_pack4(v0, lh[wave]);
        w.y = quant_pack4(v1, lh[wave]);
        w.z = quant_pack4(v2, lh[wave]);
        w.w = quant_pack4(v3, lh[wave]);
        if (STORE_IDX) idx16_out[c] = w;
    }
    // tail (n % 16) — block 0, folded into its LDS hist before the flush
    if (blockIdx.x == 0 && tid == 0) {
        for (int j = n16 * 16; j < n; ++j) {
            int b = quant_idx(src[j]);
            atomicAdd(&lh[0][b], 1u);
            if (STORE_IDX) ((unsigned char*)idx16_out)[j] = (unsigned char)b;
        }
    }
    __syncthreads();
    // one atomic per bin per block, spread over 32 copies (zeroed by memset)
    unsigned int s = lh[0][tid] + lh[1][tid] + lh[2][tid] + lh[3][tid];
    if (s) atomicAdd(&copies[(blockIdx.x & (HIST_COPIES - 1)) * NBINS + tid], s);
}

// ---- per-block LUT prologue: sum 32 copies + scan + erff + lower_bound.
__device__ __forceinline__ void build_lut(
    const unsigned int* __restrict__ copies, float* luts /*LDS[256]*/,
    float* ncdf /*LDS[256]*/, unsigned int* wsum /*LDS[4]*/) {
    const int tid = threadIdx.x;
    const int wave = tid >> 6;
    unsigned int hv = 0;
#pragma unroll
    for (int c = 0; c < HIST_COPIES; ++c) hv += copies[c * NBINS + tid];
    // inclusive scan across 256 threads
    unsigned int v = hv;
    for (int d = 1; d < 64; d <<= 1) {
        unsigned int o = __shfl_up(v, d, 64);
        if ((tid & 63) >= d) v += o;
    }
    if ((tid & 63) == 63) wsum[wave] = v;
    __syncthreads();
    unsigned int add = 0;
    for (int w = 0; w < wave; ++w) add += wsum[w];
    v += add;
    const float total = (float)(wsum[0] + wsum[1] + wsum[2] + wsum[3]);
    const float sv = (float)v / total;

    // linspace(-1,1,256); norm.cdf(x,0,0.2) = 0.5*(1+erf(x/(0.2*sqrt(2))))
    const float x = ((float)tid * 2.0f - 255.0f) / 255.0f;
    const float nc = 0.5f * (1.0f + erff(x * 3.5355339059327378f));
    const float nc255 = 0.5f * (1.0f + erff(3.5355339059327378f));
    ncdf[tid] = nc / nc255;
    __syncthreads();
    // searchsorted side='left' == lower_bound
    int lo = 0, hi = NBINS;
    while (lo < hi) {
        int m = (lo + hi) >> 1;
        if (ncdf[m] < sv) lo = m + 1; else hi = m;
    }
    luts[tid] = (float)lo * (2.0f / 255.0f) - 1.0f;   // pre-apply final rescale
    __syncthreads();
}

__device__ __forceinline__ vfloat4 lut4(const float* luts, unsigned int p) {
    vfloat4 o;
    o.x = luts[p & 255u];
    o.y = luts[(p >> 8) & 255u];
    o.z = luts[(p >> 16) & 255u];
    o.w = luts[p >> 24];
    return o;
}

// ---- Pass 2a: per-block LUT prologue + gather: one uint4 idx load (L3),
//      4 nt float4 stores per iteration.
__global__ __launch_bounds__(256) void gather_idx_kernel(
    const vuint4* __restrict__ idx16, const unsigned int* __restrict__ copies,
    vfloat4* __restrict__ out, int n16, int n, float* __restrict__ out_flat) {
    __shared__ float luts[NBINS];
    __shared__ float ncdf[NBINS];
    __shared__ unsigned int wsum[4];
    build_lut(copies, luts, ncdf, wsum);

    const int stride = gridDim.x * 256;
    for (int c = blockIdx.x * 256 + threadIdx.x; c < n16; c += stride) {
        vuint4 p = idx16[c];                       // cached load: L3-resident
        __builtin_nontemporal_store(lut4(luts, p.x), &out[4 * c + 0]);
        __builtin_nontemporal_store(lut4(luts, p.y), &out[4 * c + 1]);
        __builtin_nontemporal_store(lut4(luts, p.z), &out[4 * c + 2]);
        __builtin_nontemporal_store(lut4(luts, p.w), &out[4 * c + 3]);
    }
    if (blockIdx.x == 0 && threadIdx.x == 0) {
        const unsigned char* ib = (const unsigned char*)idx16;
        for (int j = n16 * 16; j < n; ++j) out_flat[j] = luts[ib[j]];
    }
}

// ---- Pass 2b fallback: recompute idx from source (ws too small for idx).
__global__ __launch_bounds__(256) void gather_src_kernel(
    const float* __restrict__ src, const unsigned int* __restrict__ copies,
    vfloat4* __restrict__ out, int n4, int n, float* __restrict__ out_flat) {
    __shared__ float luts[NBINS];
    __shared__ float ncdf[NBINS];
    __shared__ unsigned int wsum[4];
    build_lut(copies, luts, ncdf, wsum);

    const int stride = gridDim.x * 256;
    const vfloat4* src4 = (const vfloat4*)src;
    for (int i = blockIdx.x * 256 + threadIdx.x; i < n4; i += stride) {
        vfloat4 v = __builtin_nontemporal_load(&src4[i]);
        vfloat4 o;
        o.x = luts[quant_idx(v.x)];
        o.y = luts[quant_idx(v.y)];
        o.z = luts[quant_idx(v.z)];
        o.w = luts[quant_idx(v.w)];
        __builtin_nontemporal_store(o, &out[i]);
    }
    if (blockIdx.x == 0 && threadIdx.x == 0) {
        for (int j = n4 * 4; j < n; ++j) out_flat[j] = luts[quant_idx(src[j])];
    }
}

extern "C" void kernel_launch(void* const* d_in, const int* in_sizes, int n_in,
                              void* d_out, int out_size, void* d_ws, size_t ws_size,
                              hipStream_t stream) {
    const float* src = (const float*)d_in[0];
    const int n = in_sizes[0];
    const int n4 = n >> 2;
    const int n16 = n >> 4;
    const dim3 block(256);

    // ws layout: [0, 32KiB) hist copies | [36KiB, ...) packed u8 idx
    unsigned int* copies = (unsigned int*)d_ws;
    const size_t idx_off = 36864;
    vuint4* idx16 = (vuint4*)((char*)d_ws + idx_off);
    const bool store_idx = ws_size >= idx_off + (size_t)n;

    hipMemsetAsync(copies, 0, HIST_COPIES * NBINS * sizeof(unsigned int), stream);

    if (store_idx) {
        hist_kernel<true><<<dim3(HIST_BLOCKS), block, 0, stream>>>(
            src, copies, idx16, n16, n);
        gather_idx_kernel<<<dim3(GATH_BLOCKS), block, 0, stream>>>(
            idx16, copies, (vfloat4*)d_out, n16, n, (float*)d_out);
    } else {
        hist_kernel<false><<<dim3(HIST_BLOCKS), block, 0, stream>>>(
            src, copies, nullptr, n16, n);
        gather_src_kernel<<<dim3(GATH_BLOCKS), block, 0, stream>>>(
            src, copies, (vfloat4*)d_out, n4, n, (float*)d_out);
    }
}

// Round 12
// 123.285 us; speedup vs baseline: 3.6612x; 3.6612x over previous
//
#include <hip/hip_runtime.h>
#include <math.h>

#define NBINS 256
#define HIST_COPIES 32
#define HIST_BLOCKS 2048
#define GATH_BLOCKS 2048

typedef float vfloat4 __attribute__((ext_vector_type(4)));

__device__ __forceinline__ int quant_idx(float s) {
    // reference: clip(floor((s+1)/2*255), 0, 255)
    float t = floorf((s + 1.0f) * 0.5f * 255.0f);
    t = fminf(fmaxf(t, 0.0f), 255.0f);
    return (int)t;
}

// ---- Pass 1: LDS-privatized histogram -> 32 contention-split global copies
//      + packed-u8 idx store. nt src (stream-through), cached idx (L3).
//      Unroll 4: more instructions in flight, each lane-contiguous.
template <bool STORE_IDX>
__global__ __launch_bounds__(256) void hist_kernel(
    const float* __restrict__ src, unsigned int* __restrict__ copies,
    unsigned int* __restrict__ idx4_out, int n4, int n) {
    __shared__ unsigned int lh[4][NBINS];
    const int tid = threadIdx.x;
    const int wave = tid >> 6;
    for (int i = tid; i < 4 * NBINS; i += 256) ((unsigned int*)lh)[i] = 0u;
    __syncthreads();

    const int stride = gridDim.x * 256;
    const vfloat4* src4 = (const vfloat4*)src;
#pragma unroll 4
    for (int i = blockIdx.x * 256 + tid; i < n4; i += stride) {
        vfloat4 v = __builtin_nontemporal_load(&src4[i]);   // nt: keep L3 for idx
        int i0 = quant_idx(v.x);
        int i1 = quant_idx(v.y);
        int i2 = quant_idx(v.z);
        int i3 = quant_idx(v.w);
        atomicAdd(&lh[wave][i0], 1u);
        atomicAdd(&lh[wave][i1], 1u);
        atomicAdd(&lh[wave][i2], 1u);
        atomicAdd(&lh[wave][i3], 1u);
        if (STORE_IDX) {
            idx4_out[i] = (unsigned int)i0 | ((unsigned int)i1 << 8) |
                          ((unsigned int)i2 << 16) | ((unsigned int)i3 << 24);
        }
    }
    // tail (n % 4) — block 0, folded into its LDS hist before the flush
    if (blockIdx.x == 0 && tid == 0) {
        for (int j = n4 * 4; j < n; ++j) {
            int b = quant_idx(src[j]);
            atomicAdd(&lh[0][b], 1u);
            if (STORE_IDX) ((unsigned char*)idx4_out)[j] = (unsigned char)b;
        }
    }
    __syncthreads();
    // one atomic per bin per block, spread over 32 copies (zeroed by memset)
    unsigned int s = lh[0][tid] + lh[1][tid] + lh[2][tid] + lh[3][tid];
    if (s) atomicAdd(&copies[(blockIdx.x & (HIST_COPIES - 1)) * NBINS + tid], s);
}

// ---- per-block LUT prologue: sum 32 copies + scan + erff + lower_bound.
__device__ __forceinline__ void build_lut(
    const unsigned int* __restrict__ copies, float* luts /*LDS[256]*/,
    float* ncdf /*LDS[256]*/, unsigned int* wsum /*LDS[4]*/) {
    const int tid = threadIdx.x;
    const int wave = tid >> 6;
    unsigned int hv = 0;
#pragma unroll
    for (int c = 0; c < HIST_COPIES; ++c) hv += copies[c * NBINS + tid];
    // inclusive scan across 256 threads
    unsigned int v = hv;
    for (int d = 1; d < 64; d <<= 1) {
        unsigned int o = __shfl_up(v, d, 64);
        if ((tid & 63) >= d) v += o;
    }
    if ((tid & 63) == 63) wsum[wave] = v;
    __syncthreads();
    unsigned int add = 0;
    for (int w = 0; w < wave; ++w) add += wsum[w];
    v += add;
    const float total = (float)(wsum[0] + wsum[1] + wsum[2] + wsum[3]);
    const float sv = (float)v / total;

    // linspace(-1,1,256); norm.cdf(x,0,0.2) = 0.5*(1+erf(x/(0.2*sqrt(2))))
    const float x = ((float)tid * 2.0f - 255.0f) / 255.0f;
    const float nc = 0.5f * (1.0f + erff(x * 3.5355339059327378f));
    const float nc255 = 0.5f * (1.0f + erff(3.5355339059327378f));
    ncdf[tid] = nc / nc255;
    __syncthreads();
    // searchsorted side='left' == lower_bound
    int lo = 0, hi = NBINS;
    while (lo < hi) {
        int m = (lo + hi) >> 1;
        if (ncdf[m] < sv) lo = m + 1; else hi = m;
    }
    luts[tid] = (float)lo * (2.0f / 255.0f) - 1.0f;   // pre-apply final rescale
    __syncthreads();
}

// ---- Pass 2a: per-block LUT prologue + gather via stored u8 indices.
__global__ __launch_bounds__(256) void gather_idx_kernel(
    const unsigned int* __restrict__ idx4, const unsigned int* __restrict__ copies,
    vfloat4* __restrict__ out, int n4, int n, float* __restrict__ out_flat) {
    __shared__ float luts[NBINS];
    __shared__ float ncdf[NBINS];
    __shared__ unsigned int wsum[4];
    build_lut(copies, luts, ncdf, wsum);

    const int stride = gridDim.x * 256;
#pragma unroll 4
    for (int i = blockIdx.x * 256 + threadIdx.x; i < n4; i += stride) {
        unsigned int p = idx4[i];                  // cached load: L3-resident
        vfloat4 o;
        o.x = luts[p & 255u];
        o.y = luts[(p >> 8) & 255u];
        o.z = luts[(p >> 16) & 255u];
        o.w = luts[p >> 24];
        __builtin_nontemporal_store(o, &out[i]);   // nt: don't evict idx
    }
    if (blockIdx.x == 0 && threadIdx.x == 0) {
        const unsigned char* ib = (const unsigned char*)idx4;
        for (int j = n4 * 4; j < n; ++j) out_flat[j] = luts[ib[j]];
    }
}

// ---- Pass 2b fallback: recompute idx from source (ws too small for idx).
__global__ __launch_bounds__(256) void gather_src_kernel(
    const float* __restrict__ src, const unsigned int* __restrict__ copies,
    vfloat4* __restrict__ out, int n4, int n, float* __restrict__ out_flat) {
    __shared__ float luts[NBINS];
    __shared__ float ncdf[NBINS];
    __shared__ unsigned int wsum[4];
    build_lut(copies, luts, ncdf, wsum);

    const int stride = gridDim.x * 256;
    const vfloat4* src4 = (const vfloat4*)src;
#pragma unroll 4
    for (int i = blockIdx.x * 256 + threadIdx.x; i < n4; i += stride) {
        vfloat4 v = __builtin_nontemporal_load(&src4[i]);
        vfloat4 o;
        o.x = luts[quant_idx(v.x)];
        o.y = luts[quant_idx(v.y)];
        o.z = luts[quant_idx(v.z)];
        o.w = luts[quant_idx(v.w)];
        __builtin_nontemporal_store(o, &out[i]);
    }
    if (blockIdx.x == 0 && threadIdx.x == 0) {
        for (int j = n4 * 4; j < n; ++j) out_flat[j] = luts[quant_idx(src[j])];
    }
}

extern "C" void kernel_launch(void* const* d_in, const int* in_sizes, int n_in,
                              void* d_out, int out_size, void* d_ws, size_t ws_size,
                              hipStream_t stream) {
    const float* src = (const float*)d_in[0];
    const int n = in_sizes[0];
    const int n4 = n >> 2;
    const dim3 block(256);

    // ws layout: [0, 32KiB) hist copies | [36KiB, ...) packed u8 idx
    unsigned int* copies = (unsigned int*)d_ws;
    const size_t idx_off = 36864;
    unsigned int* idx4 = (unsigned int*)((char*)d_ws + idx_off);
    const bool store_idx = ws_size >= idx_off + (size_t)n;

    hipMemsetAsync(copies, 0, HIST_COPIES * NBINS * sizeof(unsigned int), stream);

    if (store_idx) {
        hist_kernel<true><<<dim3(HIST_BLOCKS), block, 0, stream>>>(src, copies, idx4, n4, n);
        gather_idx_kernel<<<dim3(GATH_BLOCKS), block, 0, stream>>>(
            idx4, copies, (vfloat4*)d_out, n4, n, (float*)d_out);
    } else {
        hist_kernel<false><<<dim3(HIST_BLOCKS), block, 0, stream>>>(src, copies, nullptr, n4, n);
        gather_src_kernel<<<dim3(GATH_BLOCKS), block, 0, stream>>>(
            src, copies, (vfloat4*)d_out, n4, n, (float*)d_out);
    }
}

// Round 13
// 118.503 us; speedup vs baseline: 3.8089x; 1.0403x over previous
//
#include <hip/hip_runtime.h>
#include <math.h>

#define NBINS 256
#define HIST_COPIES 32
#define HIST_BLOCKS 2048
#define GATH_BLOCKS 2048

typedef float vfloat4 __attribute__((ext_vector_type(4)));

__device__ __forceinline__ int quant_idx(float s) {
    // reference: clip(floor((s+1)/2*255), 0, 255)
    float t = floorf((s + 1.0f) * 0.5f * 255.0f);
    t = fminf(fmaxf(t, 0.0f), 255.0f);
    return (int)t;
}

// ---- Pass 1: LDS-privatized histogram -> 32 contention-split global copies
//      + packed-u8 idx store. nt src (stream-through), cached idx (L3).
template <bool STORE_IDX>
__global__ __launch_bounds__(256) void hist_kernel(
    const float* __restrict__ src, unsigned int* __restrict__ copies,
    unsigned int* __restrict__ idx4_out, int n4, int n) {
    __shared__ unsigned int lh[4][NBINS];
    const int tid = threadIdx.x;
    const int wave = tid >> 6;
    for (int i = tid; i < 4 * NBINS; i += 256) ((unsigned int*)lh)[i] = 0u;
    __syncthreads();

    const int stride = gridDim.x * 256;
    const vfloat4* src4 = (const vfloat4*)src;
    for (int i = blockIdx.x * 256 + tid; i < n4; i += stride) {
        vfloat4 v = __builtin_nontemporal_load(&src4[i]);   // nt: keep L3 for idx
        int i0 = quant_idx(v.x);
        int i1 = quant_idx(v.y);
        int i2 = quant_idx(v.z);
        int i3 = quant_idx(v.w);
        atomicAdd(&lh[wave][i0], 1u);
        atomicAdd(&lh[wave][i1], 1u);
        atomicAdd(&lh[wave][i2], 1u);
        atomicAdd(&lh[wave][i3], 1u);
        if (STORE_IDX) {
            idx4_out[i] = (unsigned int)i0 | ((unsigned int)i1 << 8) |
                          ((unsigned int)i2 << 16) | ((unsigned int)i3 << 24);
        }
    }
    // tail (n % 4) — block 0, folded into its LDS hist before the flush
    if (blockIdx.x == 0 && tid == 0) {
        for (int j = n4 * 4; j < n; ++j) {
            int b = quant_idx(src[j]);
            atomicAdd(&lh[0][b], 1u);
            if (STORE_IDX) ((unsigned char*)idx4_out)[j] = (unsigned char)b;
        }
    }
    __syncthreads();
    // one atomic per bin per block, spread over 32 copies (zeroed by memset)
    unsigned int s = lh[0][tid] + lh[1][tid] + lh[2][tid] + lh[3][tid];
    if (s) atomicAdd(&copies[(blockIdx.x & (HIST_COPIES - 1)) * NBINS + tid], s);
}

// ---- per-block LUT prologue: sum 32 copies + scan + erff + lower_bound.
__device__ __forceinline__ void build_lut(
    const unsigned int* __restrict__ copies, float* luts /*LDS[256]*/,
    float* ncdf /*LDS[256]*/, unsigned int* wsum /*LDS[4]*/) {
    const int tid = threadIdx.x;
    const int wave = tid >> 6;
    unsigned int hv = 0;
#pragma unroll
    for (int c = 0; c < HIST_COPIES; ++c) hv += copies[c * NBINS + tid];
    // inclusive scan across 256 threads
    unsigned int v = hv;
    for (int d = 1; d < 64; d <<= 1) {
        unsigned int o = __shfl_up(v, d, 64);
        if ((tid & 63) >= d) v += o;
    }
    if ((tid & 63) == 63) wsum[wave] = v;
    __syncthreads();
    unsigned int add = 0;
    for (int w = 0; w < wave; ++w) add += wsum[w];
    v += add;
    const float total = (float)(wsum[0] + wsum[1] + wsum[2] + wsum[3]);
    const float sv = (float)v / total;

    // linspace(-1,1,256); norm.cdf(x,0,0.2) = 0.5*(1+erf(x/(0.2*sqrt(2))))
    const float x = ((float)tid * 2.0f - 255.0f) / 255.0f;
    const float nc = 0.5f * (1.0f + erff(x * 3.5355339059327378f));
    const float nc255 = 0.5f * (1.0f + erff(3.5355339059327378f));
    ncdf[tid] = nc / nc255;
    __syncthreads();
    // searchsorted side='left' == lower_bound
    int lo = 0, hi = NBINS;
    while (lo < hi) {
        int m = (lo + hi) >> 1;
        if (ncdf[m] < sv) lo = m + 1; else hi = m;
    }
    luts[tid] = (float)lo * (2.0f / 255.0f) - 1.0f;   // pre-apply final rescale
    __syncthreads();
}

// ---- Pass 2a: per-block LUT prologue + gather via stored u8 indices.
//      CACHED out stores this round (single-variable test vs R9's nt).
__global__ __launch_bounds__(256) void gather_idx_kernel(
    const unsigned int* __restrict__ idx4, const unsigned int* __restrict__ copies,
    vfloat4* __restrict__ out, int n4, int n, float* __restrict__ out_flat) {
    __shared__ float luts[NBINS];
    __shared__ float ncdf[NBINS];
    __shared__ unsigned int wsum[4];
    build_lut(copies, luts, ncdf, wsum);

    const int stride = gridDim.x * 256;
    for (int i = blockIdx.x * 256 + threadIdx.x; i < n4; i += stride) {
        unsigned int p = idx4[i];                  // cached load: L3-resident
        vfloat4 o;
        o.x = luts[p & 255u];
        o.y = luts[(p >> 8) & 255u];
        o.z = luts[(p >> 16) & 255u];
        o.w = luts[p >> 24];
        out[i] = o;                                // cached store (fill-path: 7 TB/s)
    }
    if (blockIdx.x == 0 && threadIdx.x == 0) {
        const unsigned char* ib = (const unsigned char*)idx4;
        for (int j = n4 * 4; j < n; ++j) out_flat[j] = luts[ib[j]];
    }
}

// ---- Pass 2b fallback: recompute idx from source (ws too small for idx).
__global__ __launch_bounds__(256) void gather_src_kernel(
    const float* __restrict__ src, const unsigned int* __restrict__ copies,
    vfloat4* __restrict__ out, int n4, int n, float* __restrict__ out_flat) {
    __shared__ float luts[NBINS];
    __shared__ float ncdf[NBINS];
    __shared__ unsigned int wsum[4];
    build_lut(copies, luts, ncdf, wsum);

    const int stride = gridDim.x * 256;
    const vfloat4* src4 = (const vfloat4*)src;
    for (int i = blockIdx.x * 256 + threadIdx.x; i < n4; i += stride) {
        vfloat4 v = __builtin_nontemporal_load(&src4[i]);
        vfloat4 o;
        o.x = luts[quant_idx(v.x)];
        o.y = luts[quant_idx(v.y)];
        o.z = luts[quant_idx(v.z)];
        o.w = luts[quant_idx(v.w)];
        out[i] = o;
    }
    if (blockIdx.x == 0 && threadIdx.x == 0) {
        for (int j = n4 * 4; j < n; ++j) out_flat[j] = luts[quant_idx(src[j])];
    }
}

extern "C" void kernel_launch(void* const* d_in, const int* in_sizes, int n_in,
                              void* d_out, int out_size, void* d_ws, size_t ws_size,
                              hipStream_t stream) {
    const float* src = (const float*)d_in[0];
    const int n = in_sizes[0];
    const int n4 = n >> 2;
    const dim3 block(256);

    // ws layout: [0, 32KiB) hist copies | [36KiB, ...) packed u8 idx
    unsigned int* copies = (unsigned int*)d_ws;
    const size_t idx_off = 36864;
    unsigned int* idx4 = (unsigned int*)((char*)d_ws + idx_off);
    const bool store_idx = ws_size >= idx_off + (size_t)n;

    hipMemsetAsync(copies, 0, HIST_COPIES * NBINS * sizeof(unsigned int), stream);

    if (store_idx) {
        hist_kernel<true><<<dim3(HIST_BLOCKS), block, 0, stream>>>(src, copies, idx4, n4, n);
        gather_idx_kernel<<<dim3(GATH_BLOCKS), block, 0, stream>>>(
            idx4, copies, (vfloat4*)d_out, n4, n, (float*)d_out);
    } else {
        hist_kernel<false><<<dim3(HIST_BLOCKS), block, 0, stream>>>(src, copies, nullptr, n4, n);
        gather_src_kernel<<<dim3(GATH_BLOCKS), block, 0, stream>>>(
            src, copies, (vfloat4*)d_out, n4, n, (float*)d_out);
    }
}